// Round 10
// baseline (184.195 us; speedup 1.0000x reference)
//
#include <hip/hip_runtime.h>

#define B 16
#define C 128
#define NN 1024
#define KV 512
#define CHO 4

typedef _Float16 f16x8 __attribute__((ext_vector_type(8)));
typedef float f32x4 __attribute__((ext_vector_type(4)));

__device__ __forceinline__ unsigned short f2h(float v) {
  _Float16 h = (_Float16)v;
  return __builtin_bit_cast(unsigned short, h);
}
__device__ __forceinline__ unsigned int packh2(float a, float b) {
  return (unsigned int)f2h(a) | ((unsigned int)f2h(b) << 16);
}
__device__ __forceinline__ f16x8 ldcvt8(const float* __restrict__ p) {
  float4 a = *reinterpret_cast<const float4*>(p);
  float4 b = *reinterpret_cast<const float4*>(p + 4);
  f16x8 r;
  r[0] = (_Float16)a.x; r[1] = (_Float16)a.y; r[2] = (_Float16)a.z; r[3] = (_Float16)a.w;
  r[4] = (_Float16)b.x; r[5] = (_Float16)b.y; r[6] = (_Float16)b.z; r[7] = (_Float16)b.w;
  return r;
}
__device__ __forceinline__ f32x4 MFMA(f16x8 a, f16x8 b, f32x4 c) {
  return __builtin_amdgcn_mfma_f32_16x16x32_f16(a, b, c, 0, 0, 0);
}

// ---------------- K1: projections via f16 MFMA (unchanged; verified)
__global__ __launch_bounds__(256, 4) void proj_kernel(
    const float* __restrict__ x, const float* __restrict__ Wq,
    const float* __restrict__ Wk, const float* __restrict__ Wv,
    unsigned short* __restrict__ fT, unsigned short* __restrict__ gT,
    unsigned short* __restrict__ hv)
{
  int wg = blockIdx.x;
  wg = (wg & 7) * 384 + (wg >> 3);      // XCD cluster
  const int b   = wg / 192;
  const int rem = wg % 192;
  const int rt  = rem % 12;
  const int n0  = (rem / 12) * 64;

  __shared__ __align__(16) unsigned short XT[64][136];   // XT[n][c] f16

  const int t = threadIdx.x;
  const int w = t >> 6, l = t & 63, lg = l >> 4, lm = l & 15;

  {
    const float* xb = x + (size_t)b * C * NN;
    #pragma unroll
    for (int i = 0; i < 8; ++i) {
      int flat = t + i * 256;
      int c  = flat >> 4;
      int ng = flat & 15;
      float4 v = *reinterpret_cast<const float4*>(xb + (size_t)c * NN + n0 + ng * 4);
      XT[ng * 4 + 0][c] = f2h(v.x);
      XT[ng * 4 + 1][c] = f2h(v.y);
      XT[ng * 4 + 2][c] = f2h(v.z);
      XT[ng * 4 + 3][c] = f2h(v.w);
    }
  }
  __syncthreads();

  if (rt < 4) {
    const float* Wsrc = (rt < 2) ? Wq : Wk;
    unsigned short* dst = (rt < 2) ? fT : gT;
    const int c0 = (rt & 1) * 64;
    const int r  = c0 + 16 * w + lm;
    f16x8 af[4];
    #pragma unroll
    for (int c4 = 0; c4 < 4; ++c4)
      af[c4] = ldcvt8(Wsrc + (size_t)r * C + c4 * 32 + lg * 8);
    #pragma unroll
    for (int nt4 = 0; nt4 < 4; ++nt4) {
      f32x4 acc = {0.f, 0.f, 0.f, 0.f};
      #pragma unroll
      for (int c4 = 0; c4 < 4; ++c4) {
        f16x8 xb = *reinterpret_cast<const f16x8*>(&XT[16 * nt4 + lm][c4 * 32 + lg * 8]);
        acc = MFMA(af[c4], xb, acc);
      }
      int n = n0 + 16 * nt4 + lm;
      ushort4 o = { f2h(acc[0]), f2h(acc[1]), f2h(acc[2]), f2h(acc[3]) };
      *reinterpret_cast<ushort4*>(dst + ((size_t)(b * NN) + n) * C + c0 + 16 * w + 4 * lg) = o;
    }
  } else {
    const int kk = (rt - 4) * 64 + 16 * w + lm;
    f16x8 wb[4];
    #pragma unroll
    for (int c4 = 0; c4 < 4; ++c4)
      wb[c4] = ldcvt8(Wv + (size_t)kk * C + c4 * 32 + lg * 8);
    #pragma unroll
    for (int nt4 = 0; nt4 < 4; ++nt4) {
      f32x4 acc = {0.f, 0.f, 0.f, 0.f};
      #pragma unroll
      for (int c4 = 0; c4 < 4; ++c4) {
        f16x8 xa = *reinterpret_cast<const f16x8*>(&XT[16 * nt4 + lm][c4 * 32 + lg * 8]);
        acc = MFMA(xa, wb[c4], acc);
      }
      ushort4 o = { f2h(acc[0]), f2h(acc[1]), f2h(acc[2]), f2h(acc[3]) };
      *reinterpret_cast<ushort4*>(hv + ((size_t)(b * KV) + kk) * NN + n0 + 16 * nt4 + 4 * lg) = o;
    }
  }
}

// ---------------- K2: MFMA flash attention = R5 body, k-split over 4 blocks
// Grid 1024: block (b, m-tile, g). Block g owns k in [128g, 128g+128) ->
// output channel ch = g. 4 waves; wave w: QK+softmax owner of m-sub w
// (duplicated across the 4 g-blocks) + PV k-slice [128g+32w, +32).
// 16 chunks of 64 n, parity-buffered P, 1 barrier/chunk (verified R5 core).
__global__ __launch_bounds__(256, 2) void attn_kernel(
    const unsigned short* __restrict__ fT, const unsigned short* __restrict__ gT,
    const unsigned short* __restrict__ hv, const float* __restrict__ gamma,
    const float* __restrict__ mask, float* __restrict__ out)
{
  int wg = blockIdx.x;
  wg = (wg & 7) * 128 + (wg >> 3);      // XCD cluster: 2 batches per XCD
  const int b   = wg >> 6;
  const int rem = wg & 63;
  const int m0  = (rem >> 2) * 64;
  const int g   = rem & 3;

  const int t = threadIdx.x;
  const int w = t >> 6, l = t & 63, lg = l >> 4, lm = l & 15;

  __shared__ __align__(16) unsigned short P_lds[2][64][72];  // [par][m][n] f16
  __shared__ float resc_s[2][64];
  __shared__ float lsum_s[64];

  // Q frags: B operand, lane holds gT[m0+16w+lm][c4*32+8lg+i]
  f16x8 qf[4];
  {
    const unsigned short* qp = gT + ((size_t)(b * NN) + m0 + 16 * w + lm) * C + lg * 8;
    #pragma unroll
    for (int c4 = 0; c4 < 4; ++c4)
      qf[c4] = *reinterpret_cast<const f16x8*>(qp + c4 * 32);
  }

  f32x4 acc[2][4];  // [kt][mt]: k = 128g+32w+16kt+4lg+reg, m = m0+16mt+lm
  #pragma unroll
  for (int kt = 0; kt < 2; ++kt)
    #pragma unroll
    for (int mt = 0; mt < 4; ++mt)
      acc[kt][mt] = (f32x4){0.f, 0.f, 0.f, 0.f};

  float M = -3.0e38f, Lpart = 0.f;

  const unsigned short* kp = fT + ((size_t)(b * NN) + lm) * C + lg * 8;
  const unsigned short* vp = hv + ((size_t)(b * KV) + 128 * g + 32 * w + lm) * NN + lg * 8;

  #pragma unroll 1
  for (int it = 0; it < 16; ++it) {
    const int n0  = it * 64;
    const int cur = it & 1;

    // V frags early (4 x 16B; consumed after the barrier)
    f16x8 vf[2][2];
    #pragma unroll
    for (int kt = 0; kt < 2; ++kt) {
      vf[kt][0] = *reinterpret_cast<const f16x8*>(vp + (size_t)(16 * kt) * NN + n0);
      vf[kt][1] = *reinterpret_cast<const f16x8*>(vp + (size_t)(16 * kt) * NN + n0 + 32);
    }

    // QK^T (swapped): D[n][m-sub], 4 independent chains of 4
    f32x4 st[4];
    #pragma unroll
    for (int j = 0; j < 4; ++j) st[j] = (f32x4){0.f, 0.f, 0.f, 0.f};
    #pragma unroll
    for (int c4 = 0; c4 < 4; ++c4) {
      #pragma unroll
      for (int j = 0; j < 4; ++j) {
        f16x8 kf = *reinterpret_cast<const f16x8*>(kp + (size_t)(n0 + 16 * j) * C + c4 * 32);
        st[j] = MFMA(kf, qf[c4], st[j]);
      }
    }

    // online softmax over n (lane holds n = n0 + 16j + 4lg + reg, col m0+16w+lm)
    float cmax = -3.0e38f;
    #pragma unroll
    for (int j = 0; j < 4; ++j)
      cmax = fmaxf(cmax, fmaxf(fmaxf(st[j][0], st[j][1]), fmaxf(st[j][2], st[j][3])));
    cmax = fmaxf(cmax, __shfl_xor(cmax, 16, 64));
    cmax = fmaxf(cmax, __shfl_xor(cmax, 32, 64));
    float r = 1.0f;
    if (!__all(cmax <= M + 8.0f)) {       // T13 defer-rescale
      float newM = fmaxf(M, cmax);
      r = __expf(M - newM);
      M = newM;
      Lpart *= r;
    }
    float ls = 0.f;
    #pragma unroll
    for (int j = 0; j < 4; ++j) {        // exp in place (st becomes P)
      st[j][0] = __expf(st[j][0] - M);
      st[j][1] = __expf(st[j][1] - M);
      st[j][2] = __expf(st[j][2] - M);
      st[j][3] = __expf(st[j][3] - M);
      ls += (st[j][0] + st[j][1]) + (st[j][2] + st[j][3]);
    }
    Lpart += ls;
    if (lg == 0) resc_s[cur][16 * w + lm] = r;
    {
      unsigned short* prow = &P_lds[cur][16 * w + lm][0];
      #pragma unroll
      for (int j = 0; j < 4; ++j) {
        *(unsigned int*)(prow + 16 * j + 4 * lg)     = packh2(st[j][0], st[j][1]);
        *(unsigned int*)(prow + 16 * j + 4 * lg + 2) = packh2(st[j][2], st[j][3]);
      }
    }
    __syncthreads();   // the ONLY barrier per chunk

    // rescale accumulators (rare: T13)
    float rr0 = resc_s[cur][lm],      rr1 = resc_s[cur][16 + lm],
          rr2 = resc_s[cur][32 + lm], rr3 = resc_s[cur][48 + lm];
    if (!__all((rr0 == 1.f) & (rr1 == 1.f) & (rr2 == 1.f) & (rr3 == 1.f))) {
      #pragma unroll
      for (int kt = 0; kt < 2; ++kt) {
        acc[kt][0] *= rr0; acc[kt][1] *= rr1;
        acc[kt][2] *= rr2; acc[kt][3] *= rr3;
      }
    }

    // P^T B-frags: lane holds P_lds[cur][16mt+lm][32h + 8lg + i]
    f16x8 pt[4][2];
    #pragma unroll
    for (int mt = 0; mt < 4; ++mt) {
      pt[mt][0] = *reinterpret_cast<const f16x8*>(&P_lds[cur][16 * mt + lm][8 * lg]);
      pt[mt][1] = *reinterpret_cast<const f16x8*>(&P_lds[cur][16 * mt + lm][32 + 8 * lg]);
    }

    // PV: D[k][m], 16 MFMA
    #pragma unroll
    for (int kt = 0; kt < 2; ++kt)
      #pragma unroll
      for (int mt = 0; mt < 4; ++mt) {
        acc[kt][mt] = MFMA(vf[kt][0], pt[mt][0], acc[kt][mt]);
        acc[kt][mt] = MFMA(vf[kt][1], pt[mt][1], acc[kt][mt]);
      }
    // no trailing barrier: next chunk writes the other parity buffers
  }

  // denominators
  float Lp = Lpart;
  Lp += __shfl_xor(Lp, 16, 64);
  Lp += __shfl_xor(Lp, 32, 64);
  __syncthreads();
  if (lg == 0) lsum_s[16 * w + lm] = Lp;
  __syncthreads();

  const float gam = gamma[0];
  float scv[4] = { gam / lsum_s[lm],      gam / lsum_s[16 + lm],
                   gam / lsum_s[32 + lm], gam / lsum_s[48 + lm] };

  // out[b][oc][m][ch] + mask[oc][m][ch];  k = 128g+32w+16kt+4lg+reg
  // -> oc = 32w+16kt+4lg+reg, ch = g
  #pragma unroll
  for (int kt = 0; kt < 2; ++kt) {
    #pragma unroll
    for (int mt = 0; mt < 4; ++mt) {
      int m = m0 + 16 * mt + lm;
      #pragma unroll
      for (int reg = 0; reg < 4; ++reg) {
        int oc = 32 * w + 16 * kt + 4 * lg + reg;
        float v = acc[kt][mt][reg] * scv[mt] + mask[((size_t)oc * NN + m) * CHO + g];
        out[(((size_t)(b * 128 + oc)) * NN + m) * CHO + g] = v;
      }
    }
  }
}

extern "C" void kernel_launch(void* const* d_in, const int* in_sizes, int n_in,
                              void* d_out, int out_size, void* d_ws, size_t ws_size,
                              hipStream_t stream) {
  const float* x     = (const float*)d_in[0];
  const float* Wq    = (const float*)d_in[1];
  const float* Wk    = (const float*)d_in[2];
  const float* Wv    = (const float*)d_in[3];
  const float* gamma = (const float*)d_in[4];
  const float* mask  = (const float*)d_in[5];
  float* out = (float*)d_out;

  unsigned short* fT = (unsigned short*)d_ws;                 // [B][NN][C]  f16
  unsigned short* gT = fT + (size_t)B * NN * C;               // [B][NN][C]  f16
  unsigned short* hv = gT + (size_t)B * NN * C;               // [B][KV][NN] f16

  proj_kernel<<<dim3(3072), 256, 0, stream>>>(x, Wq, Wk, Wv, fT, gT, hv);
  attn_kernel<<<dim3(1024), 256, 0, stream>>>(fT, gT, hv, gamma, mask, out);
}

// Round 11
// 134.994 us; speedup vs baseline: 1.3645x; 1.3645x over previous
//
#include <hip/hip_runtime.h>

#define B 16
#define C 128
#define NN 1024
#define KV 512
#define CHO 4

typedef _Float16 f16x8 __attribute__((ext_vector_type(8)));
typedef float f32x4 __attribute__((ext_vector_type(4)));

__device__ __forceinline__ unsigned short f2h(float v) {
  _Float16 h = (_Float16)v;
  return __builtin_bit_cast(unsigned short, h);
}
__device__ __forceinline__ unsigned int packh2(float a, float b) {
  return (unsigned int)f2h(a) | ((unsigned int)f2h(b) << 16);
}
__device__ __forceinline__ f16x8 ldcvt8(const float* __restrict__ p) {
  float4 a = *reinterpret_cast<const float4*>(p);
  float4 b = *reinterpret_cast<const float4*>(p + 4);
  f16x8 r;
  r[0] = (_Float16)a.x; r[1] = (_Float16)a.y; r[2] = (_Float16)a.z; r[3] = (_Float16)a.w;
  r[4] = (_Float16)b.x; r[5] = (_Float16)b.y; r[6] = (_Float16)b.z; r[7] = (_Float16)b.w;
  return r;
}
__device__ __forceinline__ f32x4 MFMA(f16x8 a, f16x8 b, f32x4 c) {
  return __builtin_amdgcn_mfma_f32_16x16x32_f16(a, b, c, 0, 0, 0);
}

// ---------------- K1: projections via f16 MFMA (unchanged; verified)
__global__ __launch_bounds__(256, 4) void proj_kernel(
    const float* __restrict__ x, const float* __restrict__ Wq,
    const float* __restrict__ Wk, const float* __restrict__ Wv,
    unsigned short* __restrict__ fT, unsigned short* __restrict__ gT,
    unsigned short* __restrict__ hv)
{
  int wg = blockIdx.x;
  wg = (wg & 7) * 384 + (wg >> 3);      // XCD cluster
  const int b   = wg / 192;
  const int rem = wg % 192;
  const int rt  = rem % 12;
  const int n0  = (rem / 12) * 64;

  __shared__ __align__(16) unsigned short XT[64][136];   // XT[n][c] f16

  const int t = threadIdx.x;
  const int w = t >> 6, l = t & 63, lg = l >> 4, lm = l & 15;

  {
    const float* xb = x + (size_t)b * C * NN;
    #pragma unroll
    for (int i = 0; i < 8; ++i) {
      int flat = t + i * 256;
      int c  = flat >> 4;
      int ng = flat & 15;
      float4 v = *reinterpret_cast<const float4*>(xb + (size_t)c * NN + n0 + ng * 4);
      XT[ng * 4 + 0][c] = f2h(v.x);
      XT[ng * 4 + 1][c] = f2h(v.y);
      XT[ng * 4 + 2][c] = f2h(v.z);
      XT[ng * 4 + 3][c] = f2h(v.w);
    }
  }
  __syncthreads();

  if (rt < 4) {
    const float* Wsrc = (rt < 2) ? Wq : Wk;
    unsigned short* dst = (rt < 2) ? fT : gT;
    const int c0 = (rt & 1) * 64;
    const int r  = c0 + 16 * w + lm;
    f16x8 af[4];
    #pragma unroll
    for (int c4 = 0; c4 < 4; ++c4)
      af[c4] = ldcvt8(Wsrc + (size_t)r * C + c4 * 32 + lg * 8);
    #pragma unroll
    for (int nt4 = 0; nt4 < 4; ++nt4) {
      f32x4 acc = {0.f, 0.f, 0.f, 0.f};
      #pragma unroll
      for (int c4 = 0; c4 < 4; ++c4) {
        f16x8 xb = *reinterpret_cast<const f16x8*>(&XT[16 * nt4 + lm][c4 * 32 + lg * 8]);
        acc = MFMA(af[c4], xb, acc);
      }
      int n = n0 + 16 * nt4 + lm;
      ushort4 o = { f2h(acc[0]), f2h(acc[1]), f2h(acc[2]), f2h(acc[3]) };
      *reinterpret_cast<ushort4*>(dst + ((size_t)(b * NN) + n) * C + c0 + 16 * w + 4 * lg) = o;
    }
  } else {
    const int kk = (rt - 4) * 64 + 16 * w + lm;
    f16x8 wb[4];
    #pragma unroll
    for (int c4 = 0; c4 < 4; ++c4)
      wb[c4] = ldcvt8(Wv + (size_t)kk * C + c4 * 32 + lg * 8);
    #pragma unroll
    for (int nt4 = 0; nt4 < 4; ++nt4) {
      f32x4 acc = {0.f, 0.f, 0.f, 0.f};
      #pragma unroll
      for (int c4 = 0; c4 < 4; ++c4) {
        f16x8 xa = *reinterpret_cast<const f16x8*>(&XT[16 * nt4 + lm][c4 * 32 + lg * 8]);
        acc = MFMA(xa, wb[c4], acc);
      }
      ushort4 o = { f2h(acc[0]), f2h(acc[1]), f2h(acc[2]), f2h(acc[3]) };
      *reinterpret_cast<ushort4*>(hv + ((size_t)(b * KV) + kk) * NN + n0 + 16 * nt4 + 4 * lg) = o;
    }
  }
}

// ---------------- K2: MFMA flash attention — R5 body, 8 waves, dup=2, no spill
// Block: 64 m-cols, 8 waves (512 thr, 2 waves/SIMD). Wave w: QK+softmax for
// m-sub (w&3) (dup=2 across w and w+4; only w<4 write P/resc/lsum) + PV
// k-slice [64w, 64w+64). 16 chunks of 64 n, parity-buffered P, 1 barrier/chunk.
__global__ __launch_bounds__(512, 2) void attn_kernel(
    const unsigned short* __restrict__ fT, const unsigned short* __restrict__ gT,
    const unsigned short* __restrict__ hv, const float* __restrict__ gamma,
    const float* __restrict__ mask, float* __restrict__ out)
{
  int wg = blockIdx.x;
  wg = (wg & 7) * 32 + (wg >> 3);       // XCD cluster: 2 batches per XCD
  const int b  = wg >> 4;
  const int m0 = (wg & 15) * 64;

  const int t = threadIdx.x;
  const int w = t >> 6, l = t & 63, lg = l >> 4, lm = l & 15;
  const int ms = w & 3;                 // m-sub this wave softmaxes (dup pair: w, w+4)

  __shared__ __align__(16) unsigned short P_lds[2][64][72];  // [par][m][n] f16
  __shared__ float resc_s[2][64];
  __shared__ float lsum_s[64];

  // Q frags: B operand, lane holds gT[m0+16ms+lm][c4*32+8lg+i]
  f16x8 qf[4];
  {
    const unsigned short* qp = gT + ((size_t)(b * NN) + m0 + 16 * ms + lm) * C + lg * 8;
    #pragma unroll
    for (int c4 = 0; c4 < 4; ++c4)
      qf[c4] = *reinterpret_cast<const f16x8*>(qp + c4 * 32);
  }

  f32x4 acc[4][4];  // [kt][mt]: k = 64w+16kt+4lg+reg, m = m0+16mt+lm
  #pragma unroll
  for (int kt = 0; kt < 4; ++kt)
    #pragma unroll
    for (int mt = 0; mt < 4; ++mt)
      acc[kt][mt] = (f32x4){0.f, 0.f, 0.f, 0.f};

  float M = -3.0e38f, Lpart = 0.f;

  const unsigned short* kp = fT + ((size_t)(b * NN) + lm) * C + lg * 8;
  const unsigned short* vp = hv + ((size_t)(b * KV) + 64 * w + lm) * NN + lg * 8;

  #pragma unroll 1
  for (int it = 0; it < 16; ++it) {
    const int n0  = it * 64;
    const int cur = it & 1;

    // V frags early (8 x 16B; consumed after the barrier)
    f16x8 vf[4][2];
    #pragma unroll
    for (int kt = 0; kt < 4; ++kt) {
      vf[kt][0] = *reinterpret_cast<const f16x8*>(vp + (size_t)(16 * kt) * NN + n0);
      vf[kt][1] = *reinterpret_cast<const f16x8*>(vp + (size_t)(16 * kt) * NN + n0 + 32);
    }

    // QK^T (swapped): D[n][m-sub ms], 4 independent chains of 4
    f32x4 st[4];
    #pragma unroll
    for (int j = 0; j < 4; ++j) st[j] = (f32x4){0.f, 0.f, 0.f, 0.f};
    #pragma unroll
    for (int c4 = 0; c4 < 4; ++c4) {
      #pragma unroll
      for (int j = 0; j < 4; ++j) {
        f16x8 kf = *reinterpret_cast<const f16x8*>(kp + (size_t)(n0 + 16 * j) * C + c4 * 32);
        st[j] = MFMA(kf, qf[c4], st[j]);
      }
    }

    // online softmax over n (lane holds n = n0+16j+4lg+reg, col m0+16ms+lm)
    float cmax = -3.0e38f;
    #pragma unroll
    for (int j = 0; j < 4; ++j)
      cmax = fmaxf(cmax, fmaxf(fmaxf(st[j][0], st[j][1]), fmaxf(st[j][2], st[j][3])));
    cmax = fmaxf(cmax, __shfl_xor(cmax, 16, 64));
    cmax = fmaxf(cmax, __shfl_xor(cmax, 32, 64));
    float r = 1.0f;
    if (!__all(cmax <= M + 8.0f)) {       // T13 defer-rescale
      float newM = fmaxf(M, cmax);
      r = __expf(M - newM);
      M = newM;
      Lpart *= r;
    }
    float ls = 0.f;
    #pragma unroll
    for (int j = 0; j < 4; ++j) {        // exp in place (st becomes P)
      st[j][0] = __expf(st[j][0] - M);
      st[j][1] = __expf(st[j][1] - M);
      st[j][2] = __expf(st[j][2] - M);
      st[j][3] = __expf(st[j][3] - M);
      ls += (st[j][0] + st[j][1]) + (st[j][2] + st[j][3]);
    }
    Lpart += ls;
    if (w < 4) {
      if (lg == 0) resc_s[cur][16 * ms + lm] = r;
      unsigned short* prow = &P_lds[cur][16 * ms + lm][0];
      #pragma unroll
      for (int j = 0; j < 4; ++j) {
        *(unsigned int*)(prow + 16 * j + 4 * lg)     = packh2(st[j][0], st[j][1]);
        *(unsigned int*)(prow + 16 * j + 4 * lg + 2) = packh2(st[j][2], st[j][3]);
      }
    }
    __syncthreads();   // the ONLY barrier per chunk

    // rescale accumulators (rare: T13)
    float rr0 = resc_s[cur][lm],      rr1 = resc_s[cur][16 + lm],
          rr2 = resc_s[cur][32 + lm], rr3 = resc_s[cur][48 + lm];
    if (!__all((rr0 == 1.f) & (rr1 == 1.f) & (rr2 == 1.f) & (rr3 == 1.f))) {
      #pragma unroll
      for (int kt = 0; kt < 4; ++kt) {
        acc[kt][0] *= rr0; acc[kt][1] *= rr1;
        acc[kt][2] *= rr2; acc[kt][3] *= rr3;
      }
    }

    // P^T B-frags: lane holds P_lds[cur][16mt+lm][32h + 8lg + i]
    f16x8 pt[4][2];
    #pragma unroll
    for (int mt = 0; mt < 4; ++mt) {
      pt[mt][0] = *reinterpret_cast<const f16x8*>(&P_lds[cur][16 * mt + lm][8 * lg]);
      pt[mt][1] = *reinterpret_cast<const f16x8*>(&P_lds[cur][16 * mt + lm][32 + 8 * lg]);
    }

    // PV: D[k][m], 32 MFMA
    #pragma unroll
    for (int kt = 0; kt < 4; ++kt)
      #pragma unroll
      for (int mt = 0; mt < 4; ++mt) {
        acc[kt][mt] = MFMA(vf[kt][0], pt[mt][0], acc[kt][mt]);
        acc[kt][mt] = MFMA(vf[kt][1], pt[mt][1], acc[kt][mt]);
      }
    // no trailing barrier: next chunk writes the other parity buffers
  }

  // denominators (dup pair computes same value; w<4 writes)
  float Lp = Lpart;
  Lp += __shfl_xor(Lp, 16, 64);
  Lp += __shfl_xor(Lp, 32, 64);
  __syncthreads();
  if (w < 4 && lg == 0) lsum_s[16 * ms + lm] = Lp;
  __syncthreads();

  const float gam = gamma[0];
  float scv[4] = { gam / lsum_s[lm],      gam / lsum_s[16 + lm],
                   gam / lsum_s[32 + lm], gam / lsum_s[48 + lm] };

  // out[b][oc][m][ch] + mask[oc][m][ch];  k = 64w+16kt+4lg+reg, oc=k&127, ch=k>>7
  #pragma unroll
  for (int kt = 0; kt < 4; ++kt) {
    #pragma unroll
    for (int mt = 0; mt < 4; ++mt) {
      int m = m0 + 16 * mt + lm;
      #pragma unroll
      for (int reg = 0; reg < 4; ++reg) {
        int k  = 64 * w + 16 * kt + 4 * lg + reg;
        int oc = k & 127, ch = k >> 7;
        float v = acc[kt][mt][reg] * scv[mt] + mask[((size_t)oc * NN + m) * CHO + ch];
        out[(((size_t)(b * 128 + oc)) * NN + m) * CHO + ch] = v;
      }
    }
  }
}

extern "C" void kernel_launch(void* const* d_in, const int* in_sizes, int n_in,
                              void* d_out, int out_size, void* d_ws, size_t ws_size,
                              hipStream_t stream) {
  const float* x     = (const float*)d_in[0];
  const float* Wq    = (const float*)d_in[1];
  const float* Wk    = (const float*)d_in[2];
  const float* Wv    = (const float*)d_in[3];
  const float* gamma = (const float*)d_in[4];
  const float* mask  = (const float*)d_in[5];
  float* out = (float*)d_out;

  unsigned short* fT = (unsigned short*)d_ws;                 // [B][NN][C]  f16
  unsigned short* gT = fT + (size_t)B * NN * C;               // [B][NN][C]  f16
  unsigned short* hv = gT + (size_t)B * NN * C;               // [B][KV][NN] f16

  proj_kernel<<<dim3(3072), 256, 0, stream>>>(x, Wq, Wk, Wv, fT, gT, hv);
  attn_kernel<<<dim3(256), 512, 0, stream>>>(fT, gT, hv, gamma, mask, out);
}

// Round 12
// 134.090 us; speedup vs baseline: 1.3737x; 1.0067x over previous
//
#include <hip/hip_runtime.h>

#define B 16
#define C 128
#define NN 1024
#define KV 512
#define CHO 4

typedef _Float16 f16x8 __attribute__((ext_vector_type(8)));
typedef float f32x4 __attribute__((ext_vector_type(4)));

__device__ __forceinline__ unsigned short f2h(float v) {
  _Float16 h = (_Float16)v;
  return __builtin_bit_cast(unsigned short, h);
}
__device__ __forceinline__ unsigned int packh2(float a, float b) {
  return (unsigned int)f2h(a) | ((unsigned int)f2h(b) << 16);
}
__device__ __forceinline__ f16x8 ldcvt8(const float* __restrict__ p) {
  float4 a = *reinterpret_cast<const float4*>(p);
  float4 b = *reinterpret_cast<const float4*>(p + 4);
  f16x8 r;
  r[0] = (_Float16)a.x; r[1] = (_Float16)a.y; r[2] = (_Float16)a.z; r[3] = (_Float16)a.w;
  r[4] = (_Float16)b.x; r[5] = (_Float16)b.y; r[6] = (_Float16)b.z; r[7] = (_Float16)b.w;
  return r;
}
__device__ __forceinline__ f32x4 MFMA(f16x8 a, f16x8 b, f32x4 c) {
  return __builtin_amdgcn_mfma_f32_16x16x32_f16(a, b, c, 0, 0, 0);
}

// ---------------- K1: projections via f16 MFMA (unchanged; verified)
__global__ __launch_bounds__(256, 4) void proj_kernel(
    const float* __restrict__ x, const float* __restrict__ Wq,
    const float* __restrict__ Wk, const float* __restrict__ Wv,
    unsigned short* __restrict__ fT, unsigned short* __restrict__ gT,
    unsigned short* __restrict__ hv)
{
  int wg = blockIdx.x;
  wg = (wg & 7) * 384 + (wg >> 3);      // XCD cluster
  const int b   = wg / 192;
  const int rem = wg % 192;
  const int rt  = rem % 12;
  const int n0  = (rem / 12) * 64;

  __shared__ __align__(16) unsigned short XT[64][136];   // XT[n][c] f16

  const int t = threadIdx.x;
  const int w = t >> 6, l = t & 63, lg = l >> 4, lm = l & 15;

  {
    const float* xb = x + (size_t)b * C * NN;
    #pragma unroll
    for (int i = 0; i < 8; ++i) {
      int flat = t + i * 256;
      int c  = flat >> 4;
      int ng = flat & 15;
      float4 v = *reinterpret_cast<const float4*>(xb + (size_t)c * NN + n0 + ng * 4);
      XT[ng * 4 + 0][c] = f2h(v.x);
      XT[ng * 4 + 1][c] = f2h(v.y);
      XT[ng * 4 + 2][c] = f2h(v.z);
      XT[ng * 4 + 3][c] = f2h(v.w);
    }
  }
  __syncthreads();

  if (rt < 4) {
    const float* Wsrc = (rt < 2) ? Wq : Wk;
    unsigned short* dst = (rt < 2) ? fT : gT;
    const int c0 = (rt & 1) * 64;
    const int r  = c0 + 16 * w + lm;
    f16x8 af[4];
    #pragma unroll
    for (int c4 = 0; c4 < 4; ++c4)
      af[c4] = ldcvt8(Wsrc + (size_t)r * C + c4 * 32 + lg * 8);
    #pragma unroll
    for (int nt4 = 0; nt4 < 4; ++nt4) {
      f32x4 acc = {0.f, 0.f, 0.f, 0.f};
      #pragma unroll
      for (int c4 = 0; c4 < 4; ++c4) {
        f16x8 xb = *reinterpret_cast<const f16x8*>(&XT[16 * nt4 + lm][c4 * 32 + lg * 8]);
        acc = MFMA(af[c4], xb, acc);
      }
      int n = n0 + 16 * nt4 + lm;
      ushort4 o = { f2h(acc[0]), f2h(acc[1]), f2h(acc[2]), f2h(acc[3]) };
      *reinterpret_cast<ushort4*>(dst + ((size_t)(b * NN) + n) * C + c0 + 16 * w + 4 * lg) = o;
    }
  } else {
    const int kk = (rt - 4) * 64 + 16 * w + lm;
    f16x8 wb[4];
    #pragma unroll
    for (int c4 = 0; c4 < 4; ++c4)
      wb[c4] = ldcvt8(Wv + (size_t)kk * C + c4 * 32 + lg * 8);
    #pragma unroll
    for (int nt4 = 0; nt4 < 4; ++nt4) {
      f32x4 acc = {0.f, 0.f, 0.f, 0.f};
      #pragma unroll
      for (int c4 = 0; c4 < 4; ++c4) {
        f16x8 xa = *reinterpret_cast<const f16x8*>(&XT[16 * nt4 + lm][c4 * 32 + lg * 8]);
        acc = MFMA(xa, wb[c4], acc);
      }
      ushort4 o = { f2h(acc[0]), f2h(acc[1]), f2h(acc[2]), f2h(acc[3]) };
      *reinterpret_cast<ushort4*>(hv + ((size_t)(b * KV) + kk) * NN + n0 + 16 * nt4 + 4 * lg) = o;
    }
  }
}

// ---------------- K2: MFMA flash attention — R11 structure, allocator pinned
// Block: 64 m-cols, 8 waves (512 thr, 2 waves/SIMD). Wave w: QK+softmax for
// m-sub (w&3) (dup=2; only w<4 write P/resc/lsum) + PV k-slice [64w, 64w+64).
// 16 chunks of 64 n, parity-buffered P, 1 barrier/chunk.
// amdgpu_waves_per_eu(2,2): min=max=2 -> allocator targets exactly 256 VGPR
// budget, cannot shrink-and-spill (R4/R6/R7/R10/R11 failure mode).
__global__ __launch_bounds__(512)
__attribute__((amdgpu_waves_per_eu(2, 2)))
void attn_kernel(
    const unsigned short* __restrict__ fT, const unsigned short* __restrict__ gT,
    const unsigned short* __restrict__ hv, const float* __restrict__ gamma,
    const float* __restrict__ mask, float* __restrict__ out)
{
  int wg = blockIdx.x;
  wg = (wg & 7) * 32 + (wg >> 3);       // XCD cluster: 2 batches per XCD
  const int b  = wg >> 4;
  const int m0 = (wg & 15) * 64;

  const int t = threadIdx.x;
  const int w = t >> 6, l = t & 63, lg = l >> 4, lm = l & 15;
  const int ms = w & 3;                 // m-sub this wave softmaxes (dup pair: w, w+4)

  __shared__ __align__(16) unsigned short P_lds[2][64][72];  // [par][m][n] f16
  __shared__ float resc_s[2][64];
  __shared__ float lsum_s[64];

  // Q frags: B operand, lane holds gT[m0+16ms+lm][c4*32+8lg+i]
  f16x8 qf[4];
  {
    const unsigned short* qp = gT + ((size_t)(b * NN) + m0 + 16 * ms + lm) * C + lg * 8;
    #pragma unroll
    for (int c4 = 0; c4 < 4; ++c4)
      qf[c4] = *reinterpret_cast<const f16x8*>(qp + c4 * 32);
  }

  f32x4 acc[4][4];  // [kt][mt]: k = 64w+16kt+4lg+reg, m = m0+16mt+lm
  #pragma unroll
  for (int kt = 0; kt < 4; ++kt)
    #pragma unroll
    for (int mt = 0; mt < 4; ++mt)
      acc[kt][mt] = (f32x4){0.f, 0.f, 0.f, 0.f};

  float M = -3.0e38f, Lpart = 0.f;

  const unsigned short* kp = fT + ((size_t)(b * NN) + lm) * C + lg * 8;
  const unsigned short* vp = hv + ((size_t)(b * KV) + 64 * w + lm) * NN + lg * 8;

  #pragma unroll 1
  for (int it = 0; it < 16; ++it) {
    const int n0  = it * 64;
    const int cur = it & 1;

    // V frags early (8 x 16B; consumed after the barrier)
    f16x8 vf[4][2];
    #pragma unroll
    for (int kt = 0; kt < 4; ++kt) {
      vf[kt][0] = *reinterpret_cast<const f16x8*>(vp + (size_t)(16 * kt) * NN + n0);
      vf[kt][1] = *reinterpret_cast<const f16x8*>(vp + (size_t)(16 * kt) * NN + n0 + 32);
    }

    // QK^T (swapped): D[n][m-sub ms], 4 independent chains of 4
    f32x4 st[4];
    #pragma unroll
    for (int j = 0; j < 4; ++j) st[j] = (f32x4){0.f, 0.f, 0.f, 0.f};
    #pragma unroll
    for (int c4 = 0; c4 < 4; ++c4) {
      #pragma unroll
      for (int j = 0; j < 4; ++j) {
        f16x8 kf = *reinterpret_cast<const f16x8*>(kp + (size_t)(n0 + 16 * j) * C + c4 * 32);
        st[j] = MFMA(kf, qf[c4], st[j]);
      }
    }

    // online softmax over n (lane holds n = n0+16j+4lg+reg, col m0+16ms+lm)
    float cmax = -3.0e38f;
    #pragma unroll
    for (int j = 0; j < 4; ++j)
      cmax = fmaxf(cmax, fmaxf(fmaxf(st[j][0], st[j][1]), fmaxf(st[j][2], st[j][3])));
    cmax = fmaxf(cmax, __shfl_xor(cmax, 16, 64));
    cmax = fmaxf(cmax, __shfl_xor(cmax, 32, 64));
    float r = 1.0f;
    if (!__all(cmax <= M + 8.0f)) {       // T13 defer-rescale
      float newM = fmaxf(M, cmax);
      r = __expf(M - newM);
      M = newM;
      Lpart *= r;
    }
    float ls = 0.f;
    #pragma unroll
    for (int j = 0; j < 4; ++j) {        // exp in place (st becomes P)
      st[j][0] = __expf(st[j][0] - M);
      st[j][1] = __expf(st[j][1] - M);
      st[j][2] = __expf(st[j][2] - M);
      st[j][3] = __expf(st[j][3] - M);
      ls += (st[j][0] + st[j][1]) + (st[j][2] + st[j][3]);
    }
    Lpart += ls;
    if (w < 4) {
      if (lg == 0) resc_s[cur][16 * ms + lm] = r;
      unsigned short* prow = &P_lds[cur][16 * ms + lm][0];
      #pragma unroll
      for (int j = 0; j < 4; ++j) {
        *(unsigned int*)(prow + 16 * j + 4 * lg)     = packh2(st[j][0], st[j][1]);
        *(unsigned int*)(prow + 16 * j + 4 * lg + 2) = packh2(st[j][2], st[j][3]);
      }
    }
    __syncthreads();   // the ONLY barrier per chunk

    // rescale accumulators (rare: T13)
    float rr0 = resc_s[cur][lm],      rr1 = resc_s[cur][16 + lm],
          rr2 = resc_s[cur][32 + lm], rr3 = resc_s[cur][48 + lm];
    if (!__all((rr0 == 1.f) & (rr1 == 1.f) & (rr2 == 1.f) & (rr3 == 1.f))) {
      #pragma unroll
      for (int kt = 0; kt < 4; ++kt) {
        acc[kt][0] *= rr0; acc[kt][1] *= rr1;
        acc[kt][2] *= rr2; acc[kt][3] *= rr3;
      }
    }

    // P^T B-frags: lane holds P_lds[cur][16mt+lm][32h + 8lg + i]
    f16x8 pt[4][2];
    #pragma unroll
    for (int mt = 0; mt < 4; ++mt) {
      pt[mt][0] = *reinterpret_cast<const f16x8*>(&P_lds[cur][16 * mt + lm][8 * lg]);
      pt[mt][1] = *reinterpret_cast<const f16x8*>(&P_lds[cur][16 * mt + lm][32 + 8 * lg]);
    }

    // PV: D[k][m], 32 MFMA
    #pragma unroll
    for (int kt = 0; kt < 4; ++kt)
      #pragma unroll
      for (int mt = 0; mt < 4; ++mt) {
        acc[kt][mt] = MFMA(vf[kt][0], pt[mt][0], acc[kt][mt]);
        acc[kt][mt] = MFMA(vf[kt][1], pt[mt][1], acc[kt][mt]);
      }
    // no trailing barrier: next chunk writes the other parity buffers
  }

  // denominators (dup pair computes same value; w<4 writes)
  float Lp = Lpart;
  Lp += __shfl_xor(Lp, 16, 64);
  Lp += __shfl_xor(Lp, 32, 64);
  __syncthreads();
  if (w < 4 && lg == 0) lsum_s[16 * ms + lm] = Lp;
  __syncthreads();

  const float gam = gamma[0];
  float scv[4] = { gam / lsum_s[lm],      gam / lsum_s[16 + lm],
                   gam / lsum_s[32 + lm], gam / lsum_s[48 + lm] };

  // out[b][oc][m][ch] + mask[oc][m][ch];  k = 64w+16kt+4lg+reg, oc=k&127, ch=k>>7
  #pragma unroll
  for (int kt = 0; kt < 4; ++kt) {
    #pragma unroll
    for (int mt = 0; mt < 4; ++mt) {
      int m = m0 + 16 * mt + lm;
      #pragma unroll
      for (int reg = 0; reg < 4; ++reg) {
        int k  = 64 * w + 16 * kt + 4 * lg + reg;
        int oc = k & 127, ch = k >> 7;
        float v = acc[kt][mt][reg] * scv[mt] + mask[((size_t)oc * NN + m) * CHO + ch];
        out[(((size_t)(b * 128 + oc)) * NN + m) * CHO + ch] = v;
      }
    }
  }
}

extern "C" void kernel_launch(void* const* d_in, const int* in_sizes, int n_in,
                              void* d_out, int out_size, void* d_ws, size_t ws_size,
                              hipStream_t stream) {
  const float* x     = (const float*)d_in[0];
  const float* Wq    = (const float*)d_in[1];
  const float* Wk    = (const float*)d_in[2];
  const float* Wv    = (const float*)d_in[3];
  const float* gamma = (const float*)d_in[4];
  const float* mask  = (const float*)d_in[5];
  float* out = (float*)d_out;

  unsigned short* fT = (unsigned short*)d_ws;                 // [B][NN][C]  f16
  unsigned short* gT = fT + (size_t)B * NN * C;               // [B][NN][C]  f16
  unsigned short* hv = gT + (size_t)B * NN * C;               // [B][KV][NN] f16

  proj_kernel<<<dim3(3072), 256, 0, stream>>>(x, Wq, Wk, Wv, fT, gT, hv);
  attn_kernel<<<dim3(256), 512, 0, stream>>>(fT, gT, hv, gamma, mask, out);
}

// Round 13
// 117.813 us; speedup vs baseline: 1.5635x; 1.1382x over previous
//
#include <hip/hip_runtime.h>

#define B 16
#define C 128
#define NN 1024
#define KV 512
#define CHO 4

typedef _Float16 f16x8 __attribute__((ext_vector_type(8)));
typedef _Float16 f16x4 __attribute__((ext_vector_type(4)));
typedef float f32x4 __attribute__((ext_vector_type(4)));

__device__ __forceinline__ unsigned short f2h(float v) {
  _Float16 h = (_Float16)v;
  return __builtin_bit_cast(unsigned short, h);
}
__device__ __forceinline__ f16x8 ldcvt8(const float* __restrict__ p) {
  float4 a = *reinterpret_cast<const float4*>(p);
  float4 b = *reinterpret_cast<const float4*>(p + 4);
  f16x8 r;
  r[0] = (_Float16)a.x; r[1] = (_Float16)a.y; r[2] = (_Float16)a.z; r[3] = (_Float16)a.w;
  r[4] = (_Float16)b.x; r[5] = (_Float16)b.y; r[6] = (_Float16)b.z; r[7] = (_Float16)b.w;
  return r;
}
__device__ __forceinline__ f32x4 MFMA(f16x8 a, f16x8 b, f32x4 c) {
  return __builtin_amdgcn_mfma_f32_16x16x32_f16(a, b, c, 0, 0, 0);
}
// async global->LDS, 16B/lane; lds base wave-uniform (HW adds lane*16)
__device__ __forceinline__ void gld_lds16(const void* g, void* l) {
  __builtin_amdgcn_global_load_lds(
      (const __attribute__((address_space(1))) void*)g,
      (__attribute__((address_space(3))) void*)l, 16, 0, 0);
}

// ---------------- K1: projections via f16 MFMA (unchanged; verified)
__global__ __launch_bounds__(256, 4) void proj_kernel(
    const float* __restrict__ x, const float* __restrict__ Wq,
    const float* __restrict__ Wk, const float* __restrict__ Wv,
    unsigned short* __restrict__ fT, unsigned short* __restrict__ gT,
    unsigned short* __restrict__ hv)
{
  int wg = blockIdx.x;
  wg = (wg & 7) * 384 + (wg >> 3);      // XCD cluster
  const int b   = wg / 192;
  const int rem = wg % 192;
  const int rt  = rem % 12;
  const int n0  = (rem / 12) * 64;

  __shared__ __align__(16) unsigned short XT[64][136];   // XT[n][c] f16

  const int t = threadIdx.x;
  const int w = t >> 6, l = t & 63, lg = l >> 4, lm = l & 15;

  {
    const float* xb = x + (size_t)b * C * NN;
    #pragma unroll
    for (int i = 0; i < 8; ++i) {
      int flat = t + i * 256;
      int c  = flat >> 4;
      int ng = flat & 15;
      float4 v = *reinterpret_cast<const float4*>(xb + (size_t)c * NN + n0 + ng * 4);
      XT[ng * 4 + 0][c] = f2h(v.x);
      XT[ng * 4 + 1][c] = f2h(v.y);
      XT[ng * 4 + 2][c] = f2h(v.z);
      XT[ng * 4 + 3][c] = f2h(v.w);
    }
  }
  __syncthreads();

  if (rt < 4) {
    const float* Wsrc = (rt < 2) ? Wq : Wk;
    unsigned short* dst = (rt < 2) ? fT : gT;
    const int c0 = (rt & 1) * 64;
    const int r  = c0 + 16 * w + lm;
    f16x8 af[4];
    #pragma unroll
    for (int c4 = 0; c4 < 4; ++c4)
      af[c4] = ldcvt8(Wsrc + (size_t)r * C + c4 * 32 + lg * 8);
    #pragma unroll
    for (int nt4 = 0; nt4 < 4; ++nt4) {
      f32x4 acc = {0.f, 0.f, 0.f, 0.f};
      #pragma unroll
      for (int c4 = 0; c4 < 4; ++c4) {
        f16x8 xb = *reinterpret_cast<const f16x8*>(&XT[16 * nt4 + lm][c4 * 32 + lg * 8]);
        acc = MFMA(af[c4], xb, acc);
      }
      int n = n0 + 16 * nt4 + lm;
      ushort4 o = { f2h(acc[0]), f2h(acc[1]), f2h(acc[2]), f2h(acc[3]) };
      *reinterpret_cast<ushort4*>(dst + ((size_t)(b * NN) + n) * C + c0 + 16 * w + 4 * lg) = o;
    }
  } else {
    const int kk = (rt - 4) * 64 + 16 * w + lm;
    f16x8 wb[4];
    #pragma unroll
    for (int c4 = 0; c4 < 4; ++c4)
      wb[c4] = ldcvt8(Wv + (size_t)kk * C + c4 * 32 + lg * 8);
    #pragma unroll
    for (int nt4 = 0; nt4 < 4; ++nt4) {
      f32x4 acc = {0.f, 0.f, 0.f, 0.f};
      #pragma unroll
      for (int c4 = 0; c4 < 4; ++c4) {
        f16x8 xa = *reinterpret_cast<const f16x8*>(&XT[16 * nt4 + lm][c4 * 32 + lg * 8]);
        acc = MFMA(xa, wb[c4], acc);
      }
      ushort4 o = { f2h(acc[0]), f2h(acc[1]), f2h(acc[2]), f2h(acc[3]) };
      *reinterpret_cast<ushort4*>(hv + ((size_t)(b * KV) + kk) * NN + n0 + 16 * nt4 + 4 * lg) = o;
    }
  }
}

// ---------------- K2: per-wave-independent MFMA flash attention
// Block: 4 waves, 64 m-cols. Wave w owns m-sub [m0+16w,+16) COMPLETELY: QK,
// softmax (lane-local stats: col = lane&15), PV over ALL 512 kout. P never
// leaves registers (QK D-frags repacked as PV B-frags; V A-frags read from
// LDS at the matching n per slot). V tile (512x64 f16 = 64KB) staged via
// global_load_lds, parity dbuf (128KB), ONE barrier/chunk (V staging only).
__global__ __launch_bounds__(256) void attn_kernel(
    const unsigned short* __restrict__ fT, const unsigned short* __restrict__ gT,
    const unsigned short* __restrict__ hv, const float* __restrict__ gamma,
    const float* __restrict__ mask, float* __restrict__ out)
{
  int wg = blockIdx.x;
  wg = (wg & 7) * 32 + (wg >> 3);       // XCD cluster: 2 batches per XCD
  const int b  = wg >> 4;
  const int m0 = (wg & 15) * 64;

  const int t = threadIdx.x;
  const int w = t >> 6, l = t & 63, lg = l >> 4, lm = l & 15;

  __shared__ __align__(16) unsigned short vbuf[2][512][64];  // 128 KB, swizzled

  // Q frags: B operand, lane holds gT[m0+16w+lm][c4*32+8lg+i]
  f16x8 qf[4];
  {
    const unsigned short* qp = gT + ((size_t)(b * NN) + m0 + 16 * w + lm) * C + lg * 8;
    #pragma unroll
    for (int c4 = 0; c4 < 4; ++c4)
      qf[c4] = *reinterpret_cast<const f16x8*>(qp + c4 * 32);
  }

  f32x4 acc[32];  // [kt]: kout = 16kt+4lg+reg, col m = m0+16w+lm
  #pragma unroll
  for (int kt = 0; kt < 32; ++kt) acc[kt] = (f32x4){0.f, 0.f, 0.f, 0.f};

  float M = -3.0e38f, Lpart = 0.f;

  const unsigned short* kp = fT + ((size_t)(b * NN) + lm) * C + lg * 8;
  const char* hvb = (const char*)(hv + (size_t)b * KV * NN);   // row = 2048 B

  // staging geometry (chunk-invariant)
  const int skout = (t >> 3);                 // + 32q
  const int sswzb = (t & 7) * 16;             // 16B unit within 128B row
  char* const lds0 = (char*)&vbuf[0][0][0] + w * 1024;  // + q*4096 (+65536 buf1)

  // ---- prologue: stage V chunk 0 into buf 0
  #pragma unroll
  for (int q = 0; q < 16; ++q) {
    int kout = q * 32 + skout;
    int swz  = sswzb ^ ((kout & 7) << 4);
    gld_lds16(hvb + (size_t)kout * 2048 + swz, lds0 + q * 4096);
  }
  __syncthreads();

  // PV read addressing (chunk-invariant): addr = buf + kt*2048 + lm*128 + (off^sw)
  const int sw = (lm & 7) << 4;
  const char* const vrow0 = (const char*)&vbuf[0][0][0] + lm * 128;
  const int o00 = (8 * lg) ^ sw,        o01 = (32 + 8 * lg) ^ sw;
  const int o10 = (64 + 8 * lg) ^ sw,   o11 = (96 + 8 * lg) ^ sw;

  #pragma unroll 1
  for (int it = 0; it < 16; ++it) {
    const int cur = it & 1;
    const int n0  = it * 64;
    const int n1  = ((it + 1) & 15) * 64;   // wraps harmlessly at it=15

    // a) issue async staging of V(it+1) -> buf[cur^1]
    {
      char* const ldsn = lds0 + (cur ^ 1) * 65536;
      #pragma unroll
      for (int q = 0; q < 16; ++q) {
        int kout = q * 32 + skout;
        int swz  = sswzb ^ ((kout & 7) << 4);
        gld_lds16(hvb + (size_t)kout * 2048 + (size_t)n1 * 2 + swz, ldsn + q * 4096);
      }
    }

    // b) QK^T (swapped): D[n][m], K loads batched 2 j at a time
    f32x4 st[4];
    #pragma unroll
    for (int j = 0; j < 4; ++j) st[j] = (f32x4){0.f, 0.f, 0.f, 0.f};
    #pragma unroll
    for (int jp = 0; jp < 2; ++jp) {
      f16x8 kfr[2][4];
      #pragma unroll
      for (int jj = 0; jj < 2; ++jj)
        #pragma unroll
        for (int c4 = 0; c4 < 4; ++c4)
          kfr[jj][c4] = *reinterpret_cast<const f16x8*>(
              kp + (size_t)(n0 + 16 * (2 * jp + jj)) * C + c4 * 32);
      #pragma unroll
      for (int jj = 0; jj < 2; ++jj)
        #pragma unroll
        for (int c4 = 0; c4 < 4; ++c4)
          st[2 * jp + jj] = MFMA(kfr[jj][c4], qf[c4], st[2 * jp + jj]);
    }

    // c) online softmax over n (lane-local col m; stats reduced across lg)
    float cmax = -3.0e38f;
    #pragma unroll
    for (int j = 0; j < 4; ++j)
      cmax = fmaxf(cmax, fmaxf(fmaxf(st[j][0], st[j][1]), fmaxf(st[j][2], st[j][3])));
    cmax = fmaxf(cmax, __shfl_xor(cmax, 16, 64));
    cmax = fmaxf(cmax, __shfl_xor(cmax, 32, 64));
    float r = 1.0f;
    if (!__all(cmax <= M + 8.0f)) {       // T13 defer-rescale
      float newM = fmaxf(M, cmax);
      r = __expf(M - newM);
      M = newM;
      Lpart *= r;
    }
    float ls = 0.f;
    #pragma unroll
    for (int j = 0; j < 4; ++j) {        // exp in place (st becomes P)
      st[j][0] = __expf(st[j][0] - M);
      st[j][1] = __expf(st[j][1] - M);
      st[j][2] = __expf(st[j][2] - M);
      st[j][3] = __expf(st[j][3] - M);
      ls += (st[j][0] + st[j][1]) + (st[j][2] + st[j][3]);
    }
    Lpart += ls;

    // d) rescale accumulator (rare: T13); r is this lane's column factor
    if (!__all(r == 1.0f)) {
      #pragma unroll
      for (int kt = 0; kt < 32; ++kt) acc[kt] *= r;
    }

    // e) pack P as PV B-frags in-register
    f16x8 pb0, pb1;
    #pragma unroll
    for (int i = 0; i < 4; ++i) {
      pb0[i]     = (_Float16)st[0][i];
      pb0[i + 4] = (_Float16)st[1][i];
      pb1[i]     = (_Float16)st[2][i];
      pb1[i + 4] = (_Float16)st[3][i];
    }

    // f) PV from LDS V: 32 ktiles x 2 MFMA (A slot n == pb slot n)
    {
      const char* vr = vrow0 + cur * 65536;
      #pragma unroll
      for (int kt = 0; kt < 32; ++kt) {
        const char* rp = vr + kt * 2048;
        f16x4 a00 = *reinterpret_cast<const f16x4*>(rp + o00);
        f16x4 a01 = *reinterpret_cast<const f16x4*>(rp + o01);
        f16x4 a10 = *reinterpret_cast<const f16x4*>(rp + o10);
        f16x4 a11 = *reinterpret_cast<const f16x4*>(rp + o11);
        f16x8 af0 = __builtin_shufflevector(a00, a01, 0, 1, 2, 3, 4, 5, 6, 7);
        f16x8 af1 = __builtin_shufflevector(a10, a11, 0, 1, 2, 3, 4, 5, 6, 7);
        acc[kt] = MFMA(af0, pb0, acc[kt]);
        acc[kt] = MFMA(af1, pb1, acc[kt]);
      }
    }

    // g) the ONLY barrier: drains ds_reads (before buf[cur] is re-staged next
    //    body) and drains this body's staging (buf[cur^1] ready)
    __syncthreads();
  }

  // denominators fully in-register
  float Lp = Lpart;
  Lp += __shfl_xor(Lp, 16, 64);
  Lp += __shfl_xor(Lp, 32, 64);
  const float scv = gamma[0] / Lp;

  // epilogue: out[b][oc][m][ch] + mask;  kout = 16kt+4lg+reg, m = m0+16w+lm
  const int m = m0 + 16 * w + lm;
  #pragma unroll
  for (int kt = 0; kt < 32; ++kt) {
    #pragma unroll
    for (int reg = 0; reg < 4; ++reg) {
      int kout = 16 * kt + 4 * lg + reg;
      int oc = kout & 127, ch = kout >> 7;
      float v = acc[kt][reg] * scv + mask[((size_t)oc * NN + m) * CHO + ch];
      out[(((size_t)(b * 128 + oc)) * NN + m) * CHO + ch] = v;
    }
  }
}

extern "C" void kernel_launch(void* const* d_in, const int* in_sizes, int n_in,
                              void* d_out, int out_size, void* d_ws, size_t ws_size,
                              hipStream_t stream) {
  const float* x     = (const float*)d_in[0];
  const float* Wq    = (const float*)d_in[1];
  const float* Wk    = (const float*)d_in[2];
  const float* Wv    = (const float*)d_in[3];
  const float* gamma = (const float*)d_in[4];
  const float* mask  = (const float*)d_in[5];
  float* out = (float*)d_out;

  unsigned short* fT = (unsigned short*)d_ws;                 // [B][NN][C]  f16
  unsigned short* gT = fT + (size_t)B * NN * C;               // [B][NN][C]  f16
  unsigned short* hv = gT + (size_t)B * NN * C;               // [B][KV][NN] f16

  proj_kernel<<<dim3(3072), 256, 0, stream>>>(x, Wq, Wk, Wv, fT, gT, hv);
  attn_kernel<<<dim3(256), 256, 0, stream>>>(fT, gT, hv, gamma, mask, out);
}